// Round 12
// baseline (176.005 us; speedup 1.0000x reference)
//
#include <hip/hip_runtime.h>

#define B_ 4
#define T_ 1024
#define C_ 768
#define H_ 12
#define D_ 64

typedef unsigned short u16;
typedef __attribute__((ext_vector_type(8))) short b16x8;   // 8 bf16 (4 VGPRs)
typedef __attribute__((ext_vector_type(4))) float f32x4;   // MFMA C/D

#define MFMA(a, b, c) __builtin_amdgcn_mfma_f32_16x16x32_bf16(a, b, c, 0, 0, 0)

__device__ __forceinline__ float b2f(u16 u) {
    return __uint_as_float(((unsigned)u) << 16);
}
__device__ __forceinline__ u16 f2b(float f) {
    unsigned u = __float_as_uint(f);
    u += 0x7fffu + ((u >> 16) & 1u);   // round-to-nearest-even
    return (u16)(u >> 16);
}
__device__ __forceinline__ u16 f2b_tr(float f) {    // truncate (cheap)
    return (u16)(__float_as_uint(f) >> 16);
}

// async global->LDS, 16B per lane; LDS dest = wave-uniform base + lane*16
__device__ __forceinline__ void g2l16(const u16* g, u16* l) {
    __builtin_amdgcn_global_load_lds(
        (const __attribute__((address_space(1))) unsigned int*)g,
        (__attribute__((address_space(3))) unsigned int*)l, 16, 0, 0);
}

// ---------------------------------------------------------------------------
// Fused input conversion:
//   blocks [0, 2304): fp32 -> bf16 weight convert (4 matrices into wb)
//   blocks [2304, 3072): x (B,C,T) fp32 -> xb (B,T,C) bf16 (LDS transpose)
// ---------------------------------------------------------------------------
__global__ __launch_bounds__(256) void conv_fused_kernel(
    const float* __restrict__ w0, const float* __restrict__ w1,
    const float* __restrict__ w2, const float* __restrict__ w3,
    u16* __restrict__ wb, const float* __restrict__ x, u16* __restrict__ xb)
{
    __shared__ u16 tile[64][68];
    const int bx = blockIdx.x;
    const int tid = threadIdx.x;

    if (bx < 2304) {
        const int mat = bx / 576;
        const float* src = mat == 0 ? w0 : mat == 1 ? w1 : mat == 2 ? w2 : w3;
        u16* dst = wb + (size_t)mat * C_ * C_;
        const int i = ((bx % 576) * 256 + tid) * 4;
        float4 v = *(const float4*)(src + i);
        ushort4 st = {f2b(v.x), f2b(v.y), f2b(v.z), f2b(v.w)};
        *(ushort4*)(dst + i) = st;
        return;
    }

    const int cx = bx - 2304;
    const int t0 = (cx & 15) * 64;
    const int c0 = ((cx >> 4) % 12) * 64;
    const int b  = cx / 192;
    #pragma unroll
    for (int p = 0; p < 4; ++p) {
        const int cc = p * 16 + (tid >> 4);
        const int t4 = (tid & 15) * 4;
        float4 v = *(const float4*)(x + ((size_t)b * C_ + c0 + cc) * T_ + t0 + t4);
        tile[t4 + 0][cc] = f2b(v.x);
        tile[t4 + 1][cc] = f2b(v.y);
        tile[t4 + 2][cc] = f2b(v.z);
        tile[t4 + 3][cc] = f2b(v.w);
    }
    __syncthreads();
    #pragma unroll
    for (int p = 0; p < 4; ++p) {
        const int tt = p * 16 + (tid >> 4);
        const int c4 = (tid & 15) * 4;
        ushort4 st = *(const ushort4*)&tile[tt][c4];
        *(ushort4*)(xb + ((size_t)b * T_ + t0 + tt) * C_ + c0 + c4) = st;
    }
}

// ---------------------------------------------------------------------------
// Fused QKV projection, MFMA bf16, BK=32. Tile 128(o) x 128(t).
// Q (log2e-scaled), K -> bf16 (B,H,T,d) coalesced.
// V -> transposed IN-KERNEL through an LDS tile and stored (B,H,D,T) with
// 16B-coalesced stores (transv kernel eliminated).
// ---------------------------------------------------------------------------
__global__ __launch_bounds__(256) void qkv_mfma_kernel(
    const u16* __restrict__ wb, const u16* __restrict__ xb,
    const float* __restrict__ b_q, const float* __restrict__ b_k,
    const float* __restrict__ b_v,
    u16* __restrict__ q_ws, u16* __restrict__ k_ws, u16* __restrict__ vT_ws)
{
    // smem carve: [a_s: 128*32][b_s: 128*32] overlaid by vt[128][136] epilogue
    __shared__ __align__(16) u16 smem[128 * 136];
    u16* a_s = smem;
    u16* b_s = smem + 128 * 32;

    const int tid = threadIdx.x;
    const int wv = tid >> 6, lane = tid & 63;
    const int lo = lane & 15, quad = lane >> 4;
    const int wm = wv >> 1, wn = wv & 1;
    const int swz = (lo >> 1) & 3;
    const int srow = lane >> 2;                       // staging row within instr
    const int skb  = (lane & 3) ^ ((lane >> 3) & 3);  // staged k-block (swizzled)

    const int t0 = blockIdx.x * 128;
    const int mat = blockIdx.y / 6, oy = blockIdx.y % 6;
    const int o0 = oy * 128;
    const int b  = blockIdx.z;

    const u16* A = wb + (size_t)mat * C_ * C_;
    const float* bias = mat == 0 ? b_q : (mat == 1 ? b_k : b_v);
    const float scale = mat == 0 ? 0.18033688f : 1.0f;   // 0.125 * log2(e)

    const size_t bT0 = (size_t)b * T_ + t0;

    f32x4 acc[4][4] = {};

    for (int kk = 0; kk < C_; kk += 32) {
        __syncthreads();
        #pragma unroll
        for (int ia = 0; ia < 2; ++ia) {
            const int row0 = (wv * 2 + ia) * 16;
            g2l16(A + (size_t)(o0 + row0 + srow) * C_ + kk + skb * 8,
                  a_s + row0 * 32);
        }
        #pragma unroll
        for (int ib = 0; ib < 2; ++ib) {
            const int row0 = (wv * 2 + ib) * 16;
            g2l16(xb + (bT0 + row0 + srow) * C_ + kk + skb * 8,
                  b_s + row0 * 32);
        }
        __syncthreads();

        b16x8 af[4], bf[4];
        #pragma unroll
        for (int mi = 0; mi < 4; ++mi) {
            const int m = wm * 64 + mi * 16 + lo;
            af[mi] = *(const b16x8*)(a_s + m * 32 + (quad ^ swz) * 8);
        }
        #pragma unroll
        for (int ni = 0; ni < 4; ++ni) {
            const int n = wn * 64 + ni * 16 + lo;
            bf[ni] = *(const b16x8*)(b_s + n * 32 + (quad ^ swz) * 8);
        }
        #pragma unroll
        for (int mi = 0; mi < 4; ++mi)
            #pragma unroll
            for (int ni = 0; ni < 4; ++ni)
                acc[mi][ni] = MFMA(af[mi], bf[ni], acc[mi][ni]);
    }

    if (mat != 2) {
        u16* dst = mat == 0 ? q_ws : k_ws;
        #pragma unroll
        for (int mi = 0; mi < 4; ++mi) {
            const int o_b = o0 + wm * 64 + mi * 16 + quad * 4;
            const float4 bv4 = *(const float4*)(bias + o_b);
            const int h = o_b >> 6;
            const int dd0 = o_b & 63;
            #pragma unroll
            for (int ni = 0; ni < 4; ++ni) {
                const int t = t0 + wn * 64 + ni * 16 + lo;
                f32x4 a = acc[mi][ni];
                ushort4 st;
                st.x = f2b((a[0] + bv4.x) * scale);
                st.y = f2b((a[1] + bv4.y) * scale);
                st.z = f2b((a[2] + bv4.z) * scale);
                st.w = f2b((a[3] + bv4.w) * scale);
                *(ushort4*)(dst + (((size_t)b * H_ + h) * T_ + t) * D_ + dd0) = st;
            }
        }
    } else {
        // V: transpose through LDS vt[o_local][t_local], stride 136 (16B-aligned
        // rows, +8 offset per row across banks), then coalesced (B,H,D,T) store.
        u16* vt = smem;
        __syncthreads();                    // a_s/b_s readers done; reuse as vt
        #pragma unroll
        for (int mi = 0; mi < 4; ++mi) {
            const int o_l = wm * 64 + mi * 16 + quad * 4;
            const float4 bv4 = *(const float4*)(bias + o0 + o_l);
            const float bb[4] = {bv4.x, bv4.y, bv4.z, bv4.w};
            #pragma unroll
            for (int ni = 0; ni < 4; ++ni) {
                const int t_l = wn * 64 + ni * 16 + lo;
                #pragma unroll
                for (int r = 0; r < 4; ++r)
                    vt[(o_l + r) * 136 + t_l] = f2b(acc[mi][ni][r] + bb[r]);
            }
        }
        __syncthreads();
        #pragma unroll
        for (int c = 0; c < 8; ++c) {
            const int idx = c * 256 + tid;
            const int row = idx >> 4, ch = idx & 15;
            const b16x8 val = *(const b16x8*)(vt + row * 136 + ch * 8);
            const int o_g = o0 + row;
            const int h = o_g >> 6, dd = o_g & 63;
            *(b16x8*)(vT_ws + (((size_t)b * H_ + h) * D_ + dd) * T_ + t0 + ch * 8) = val;
        }
    }
}

// ---------------------------------------------------------------------------
// Output projection, MFMA bf16, BK=32, tile 128(o) x 128(t) (qkv structure:
// 2x MFMA per barrier phase vs the old 64x128). Epilogue fp32 (B,C,T).
// ---------------------------------------------------------------------------
__global__ __launch_bounds__(256) void out_mfma_kernel(
    const u16* __restrict__ wob, const u16* __restrict__ ab,
    const float* __restrict__ bias, float* __restrict__ out)
{
    __shared__ __align__(16) u16 a_s[128 * 32];
    __shared__ __align__(16) u16 b_s[128 * 32];

    const int tid = threadIdx.x;
    const int wv = tid >> 6, lane = tid & 63;
    const int lo = lane & 15, quad = lane >> 4;
    const int wm = wv >> 1, wn = wv & 1;
    const int swz = (lo >> 1) & 3;
    const int srow = lane >> 2;
    const int skb  = (lane & 3) ^ ((lane >> 3) & 3);

    const int t0 = blockIdx.x * 128;
    const int o0 = blockIdx.y * 128;
    const int b  = blockIdx.z;
    const size_t bT0 = (size_t)b * T_ + t0;

    f32x4 acc[4][4] = {};

    for (int kk = 0; kk < C_; kk += 32) {
        __syncthreads();
        #pragma unroll
        for (int ia = 0; ia < 2; ++ia) {
            const int row0 = (wv * 2 + ia) * 16;
            g2l16(wob + (size_t)(o0 + row0 + srow) * C_ + kk + skb * 8,
                  a_s + row0 * 32);
        }
        #pragma unroll
        for (int ib = 0; ib < 2; ++ib) {
            const int row0 = (wv * 2 + ib) * 16;
            g2l16(ab + (bT0 + row0 + srow) * C_ + kk + skb * 8,
                  b_s + row0 * 32);
        }
        __syncthreads();

        b16x8 af[4], bf[4];
        #pragma unroll
        for (int mi = 0; mi < 4; ++mi) {
            const int m = wm * 64 + mi * 16 + lo;
            af[mi] = *(const b16x8*)(a_s + m * 32 + (quad ^ swz) * 8);
        }
        #pragma unroll
        for (int ni = 0; ni < 4; ++ni) {
            const int n = wn * 64 + ni * 16 + lo;
            bf[ni] = *(const b16x8*)(b_s + n * 32 + (quad ^ swz) * 8);
        }
        #pragma unroll
        for (int mi = 0; mi < 4; ++mi)
            #pragma unroll
            for (int ni = 0; ni < 4; ++ni)
                acc[mi][ni] = MFMA(af[mi], bf[ni], acc[mi][ni]);
    }

    #pragma unroll
    for (int mi = 0; mi < 4; ++mi) {
        const int o_b = o0 + wm * 64 + mi * 16 + quad * 4;
        const float4 bv4 = *(const float4*)(bias + o_b);
        const float bb[4] = {bv4.x, bv4.y, bv4.z, bv4.w};
        #pragma unroll
        for (int ni = 0; ni < 4; ++ni) {
            const int t = t0 + wn * 64 + ni * 16 + lo;
            f32x4 a = acc[mi][ni];
            #pragma unroll
            for (int r = 0; r < 4; ++r)
                out[((size_t)b * C_ + o_b + r) * T_ + t] = a[r] + bb[r];
        }
    }
}

// ---------------------------------------------------------------------------
// MFMA flash attention (R11, unchanged): 64-row blocks, 4 waves x 16 rows,
// j=64, no-max softmax (q log2e-scaled upstream, p = exp2(s) direct).
// ---------------------------------------------------------------------------
__global__ __launch_bounds__(256, 2) void attn_mfma_kernel(
    const u16* __restrict__ qw, const u16* __restrict__ kw, const u16* __restrict__ vw,
    const float* __restrict__ erk, const float* __restrict__ erv,
    u16* __restrict__ att)
{
    __shared__ __align__(16) u16 k_s[64 * 64];   // [j][d], 16B chunks XOR-swizzled
    __shared__ __align__(16) u16 v_s[64 * 64];   // [dd][j], swizzled
    __shared__ __align__(16) u16 p_s[64 * 64];   // [i][j], swizzled
    __shared__ float qrel_s[64][9];
    __shared__ float band_s[64][9];
    __shared__ float linv_s[64];

    const int tid = threadIdx.x;
    const int wv = tid >> 6, lane = tid & 63;
    const int lo = lane & 15, quad = lane >> 4;
    const int wi0 = wv * 16;
    const int it0 = blockIdx.x * 64;
    const int h = blockIdx.y, b = blockIdx.z;
    const int bh = b * H_ + h;

    const u16* qp = qw + (size_t)bh * T_ * D_;
    const u16* kp = kw + (size_t)bh * T_ * D_;
    const u16* vp = vw + (size_t)bh * D_ * T_;

    const int srow = lane >> 3;
    const int schunk = (lane & 7) ^ srow;
    const int lsw = lo & 7;

    b16x8 qf[2];
    #pragma unroll
    for (int kc = 0; kc < 2; ++kc)
        qf[kc] = *(const b16x8*)(qp + (size_t)(it0 + wi0 + lo) * D_ + kc * 32 + quad * 8);

    {
        b16x8 ekf[2];
        #pragma unroll
        for (int kc = 0; kc < 2; ++kc) {
            union { b16x8 v; u16 s[8]; } t;
            #pragma unroll
            for (int r = 0; r < 8; ++r) t.s[r] = 0;
            if (lo < 9) {
                const float* e = erk + lo * D_ + kc * 32 + quad * 8;
                #pragma unroll
                for (int r = 0; r < 8; ++r) t.s[r] = f2b(e[r]);
            }
            ekf[kc] = t.v;
        }
        f32x4 acc = {};
        acc = MFMA(qf[0], ekf[0], acc);
        acc = MFMA(qf[1], ekf[1], acc);
        if (lo < 9)
            #pragma unroll
            for (int r = 0; r < 4; ++r)
                qrel_s[wi0 + quad * 4 + r][lo] = acc[r];
    }

    for (int idx = lane; idx < 16 * 9; idx += 64)
        band_s[wi0 + idx / 9][idx % 9] = -1e30f;

    f32x4 o[4] = {};
    float lpart = 0.f;

    for (int jt = 0; jt < T_; jt += 64) {
        __syncthreads();
        #pragma unroll
        for (int i2 = 0; i2 < 2; ++i2) {
            const int row0 = (wv * 2 + i2) * 8;
            g2l16(kp + (size_t)(jt + row0 + srow) * D_ + schunk * 8, k_s + row0 * 64);
            g2l16(vp + (size_t)(row0 + srow) * T_ + jt + schunk * 8, v_s + row0 * 64);
        }
        __syncthreads();

        f32x4 st[4];
        #pragma unroll
        for (int mt = 0; mt < 4; ++mt) {
            const int kr = mt * 16 + lo;
            const b16x8 ka0 = *(const b16x8*)(k_s + kr * 64 + ((quad) ^ lsw) * 8);
            const b16x8 ka1 = *(const b16x8*)(k_s + kr * 64 + ((4 + quad) ^ lsw) * 8);
            f32x4 a = {};
            a = MFMA(ka0, qf[0], a);
            a = MFMA(ka1, qf[1], a);
            st[mt] = a;
        }

        if (jt >= it0 - 67 && jt <= it0 + 67) {
            const int ibase = it0 + wi0 + lo;
            #pragma unroll
            for (int mt = 0; mt < 4; ++mt)
                #pragma unroll
                for (int r = 0; r < 4; ++r) {
                    const int rr = (jt + mt * 16 + quad * 4 + r) - ibase + 4;
                    if (rr >= 0 && rr <= 8) {
                        const float s2 = st[mt][r] + qrel_s[wi0 + lo][rr];
                        st[mt][r] = s2;
                        band_s[wi0 + lo][rr] = s2;
                    }
                }
        }

        #pragma unroll
        for (int mt = 0; mt < 4; ++mt)
            #pragma unroll
            for (int r = 0; r < 4; ++r) {
                const float e = exp2f(st[mt][r]);
                st[mt][r] = e;
                lpart += e;
            }

        #pragma unroll
        for (int mt = 0; mt < 4; ++mt) {
            ushort4 pw;
            pw.x = f2b_tr(st[mt][0]);
            pw.y = f2b_tr(st[mt][1]);
            pw.z = f2b_tr(st[mt][2]);
            pw.w = f2b_tr(st[mt][3]);
            const int slot = (mt * 2 + (quad >> 1)) ^ lsw;
            *(ushort4*)(p_s + (wi0 + lo) * 64 + slot * 8 + (quad & 1) * 4) = pw;
        }

        const b16x8 pa0 = *(const b16x8*)(p_s + (wi0 + lo) * 64 + ((quad) ^ lsw) * 8);
        const b16x8 pa1 = *(const b16x8*)(p_s + (wi0 + lo) * 64 + ((4 + quad) ^ lsw) * 8);
        #pragma unroll
        for (int nd = 0; nd < 4; ++nd) {
            const int vr = nd * 16 + lo;
            const b16x8 vb0 = *(const b16x8*)(v_s + vr * 64 + ((quad) ^ lsw) * 8);
            const b16x8 vb1 = *(const b16x8*)(v_s + vr * 64 + ((4 + quad) ^ lsw) * 8);
            o[nd] = MFMA(pa0, vb0, o[nd]);
            o[nd] = MFMA(pa1, vb1, o[nd]);
        }
    }

    {
        union { b16x8 v; u16 s[8]; } tb;
        #pragma unroll
        for (int r = 0; r < 8; ++r) {
            const int rr = quad * 8 + r;
            tb.s[r] = (rr <= 8) ? f2b(exp2f(band_s[wi0 + lo][rr])) : (u16)0;
        }
        const b16x8 baf = tb.v;
        #pragma unroll
        for (int nd = 0; nd < 4; ++nd) {
            union { b16x8 v; u16 s[8]; } t;
            #pragma unroll
            for (int r = 0; r < 8; ++r) {
                const int rr = quad * 8 + r;
                t.s[r] = (rr <= 8) ? f2b(erv[rr * D_ + nd * 16 + lo]) : (u16)0;
            }
            o[nd] = MFMA(baf, t.v, o[nd]);
        }
    }

    lpart += __shfl_xor(lpart, 16);
    lpart += __shfl_xor(lpart, 32);
    if (quad == 0) linv_s[wi0 + lo] = 1.f / lpart;
    #pragma unroll
    for (int r = 0; r < 4; ++r) {
        const int il = wi0 + quad * 4 + r;
        const float inv = linv_s[il];
        const size_t base = ((size_t)b * T_ + it0 + il) * C_ + h * D_;
        #pragma unroll
        for (int nd = 0; nd < 4; ++nd)
            att[base + nd * 16 + lo] = f2b(o[nd][r] * inv);
    }
}

extern "C" void kernel_launch(void* const* d_in, const int* in_sizes, int n_in,
                              void* d_out, int out_size, void* d_ws, size_t ws_size,
                              hipStream_t stream) {
    const float* x   = (const float*)d_in[0];
    const float* w_q = (const float*)d_in[1];
    const float* b_q = (const float*)d_in[2];
    const float* w_k = (const float*)d_in[3];
    const float* b_k = (const float*)d_in[4];
    const float* w_v = (const float*)d_in[5];
    const float* b_v = (const float*)d_in[6];
    const float* w_o = (const float*)d_in[7];
    const float* b_o = (const float*)d_in[8];
    const float* erk = (const float*)d_in[9];
    const float* erv = (const float*)d_in[10];

    const size_t N = (size_t)B_ * C_ * T_;   // 3,145,728
    u16* q_ws  = (u16*)d_ws;                 // bf16 (B,H,T,d), log2e-scaled
    u16* k_ws  = q_ws + N;                   // bf16 (B,H,T,d)
    u16* a_ws  = q_ws + 2 * N;               // bf16 (B,T,C) attn out
    u16* vdT   = q_ws + 3 * N;               // bf16 (B,H,D,T) (direct from qkv)
    u16* xb    = q_ws + 4 * N;               // bf16 (B,T,C)
    u16* wb    = q_ws + 5 * N;               // bf16 4x(C,C): wq,wk,wv,wo
    float* out = (float*)d_out;

    dim3 blk(256, 1, 1);

    conv_fused_kernel<<<dim3(3072), blk, 0, stream>>>(w_q, w_k, w_v, w_o, wb, x, xb);

    qkv_mfma_kernel<<<dim3(T_ / 128, 18, B_), blk, 0, stream>>>(
        wb, xb, b_q, b_k, b_v, q_ws, k_ws, vdT);

    attn_mfma_kernel<<<dim3(T_ / 64, H_, B_), blk, 0, stream>>>(
        q_ws, k_ws, vdT, erk, erv, a_ws);

    out_mfma_kernel<<<dim3(T_ / 128, C_ / 128, B_), blk, 0, stream>>>(
        wb + 3 * (size_t)C_ * C_, a_ws, b_o, out);
}